// Round 9
// baseline (74.705 us; speedup 1.0000x reference)
//
#include <hip/hip_runtime.h>

// out[b,u] = prod_i ( x[b,i]*w[i,u] + (1 - w[i,u]) ) = prod_i ( 1 + w[i,u]*(x[b,i]-1) )
// B=2048, IN_DIM=256, UNITS=512
//
// Round 15: RESUBMIT of Round 14 (bench infra failed: "container failed
// twice" -- no data). Experiment unchanged: force VOP3P pk math.
// Evidence chain: main loop REP-measured at 13.4us; {LDS,VMEM,SMEM} operand
// paths, {4,8} waves/SIMD, {8,0} barriers all neutral. 13.4us == 8 waves x
// 2048 scalar-VALU x 2cyc / SIMD exactly => hypothesis: compiler lowers v2f
// fma/mul to SCALAR v_fma_f32/v_mul_f32 and the VALU pipe is saturated
// (masking every other lever). Inner ops are single self-contained inline-asm
// VOP3P instructions (v_pk_fma_f32 / v_pk_mul_f32, dst-tied, no cross-asm
// state -> sound, unlike R12). Everything else byte-identical to R13
// (passed, absmax 3.76e-37, 71.31us).
// Decode: dur ~64-65 => scalar-lowering confirmed+fixed; dur ~71 => pk f32 is
// half-rate on gfx950 -> main loop already at VALU roofline -> declare done.

typedef float v2f __attribute__((ext_vector_type(2)));

#define B_DIM   2048
#define IN_DIM  256
#define UNITS   512
#define BT      64      // b per block (= lanes per wave)
#define UT      32      // u per block (all 16 waves same u-tile)
#define BLOCK   1024
#define NW      16      // waves per block = i-slices
#define KIS     16      // i per wave
#define PLANE_F (64*32) // floats per combine plane (8 KB)

__global__ __launch_bounds__(BLOCK, 8) void prodw_kernel(
    const float* __restrict__ x,   // [B, IN_DIM]
    const float* __restrict__ w,   // [IN_DIM, UNITS]
    float* __restrict__ out)       // [B, UNITS]
{
    __shared__ __align__(16) float lds[(NW / 2) * PLANE_F];   // 64 KB

    const int tid  = threadIdx.x;
    const int ln   = tid & 63;                                   // lane = b
    const int wid  = __builtin_amdgcn_readfirstlane(tid >> 6);   // wave = i-slice
    const int ublk = blockIdx.x * UT;
    const int bblk = blockIdx.y * BT;

    const float* xp = x + (size_t)(bblk + ln) * IN_DIM + wid * KIS;

    // ---- y chunk 0 (i = 0..7 of this slice), registers only ----
    float yv[8];
    {
        const float4 f0 = *(const float4*)(xp + 0);
        const float4 f1 = *(const float4*)(xp + 4);
        yv[0] = f0.x - 1.0f; yv[1] = f0.y - 1.0f;
        yv[2] = f0.z - 1.0f; yv[3] = f0.w - 1.0f;
        yv[4] = f1.x - 1.0f; yv[5] = f1.y - 1.0f;
        yv[6] = f1.z - 1.0f; yv[7] = f1.w - 1.0f;
    }

    v2f acc[16];
#pragma unroll
    for (int q = 0; q < 16; ++q) acc[q] = (v2f){1.0f, 1.0f};

    const v2f one2 = (v2f){1.0f, 1.0f};

    // wave-uniform w base (all indices from readfirstlane/blockIdx)
    const float* wp = w + (size_t)(wid * KIS) * UNITS + ublk;

    // ---- main loop: zero LDS, zero barriers; FORCED VOP3P pk math ----
#pragma unroll 2
    for (int r = 0; r < KIS; ++r) {
        // reload y chunk 1 (i = 8..15) just before first use
        if (r == 8) {
            const float4 f0 = *(const float4*)(xp + 8);
            const float4 f1 = *(const float4*)(xp + 12);
            yv[0] = f0.x - 1.0f; yv[1] = f0.y - 1.0f;
            yv[2] = f0.z - 1.0f; yv[3] = f0.w - 1.0f;
            yv[4] = f1.x - 1.0f; yv[5] = f1.y - 1.0f;
            yv[6] = f1.z - 1.0f; yv[7] = f1.w - 1.0f;
        }

        const float* wr = wp + (size_t)r * UNITS;   // wave-uniform row
        const float yb = yv[r & 7];
        const v2f yy = (v2f){yb, yb};
#pragma unroll
        for (int q = 0; q < 16; ++q) {
            const v2f wv = *(const v2f*)(wr + 2 * q);
            v2f t;
            // t = wv*yy + 1.0  (packed f32, one VOP3P inst)
            asm("v_pk_fma_f32 %0, %1, %2, %3"
                : "=v"(t) : "v"(wv), "v"(yy), "v"(one2));
            // acc *= t (packed f32)
            asm("v_pk_mul_f32 %0, %0, %1"
                : "+v"(acc[q]) : "v"(t));
        }
    }

    // ---- combine across 16 waves (elementwise product), XOR-swizzled b128 ----
#pragma unroll
    for (int half = NW / 2; half >= 1; half >>= 1) {
        __syncthreads();
        if (wid >= half && wid < 2 * half) {
            float* pl = lds + (size_t)(wid - half) * PLANE_F + ln * 32;
#pragma unroll
            for (int k = 0; k < 8; ++k)
                *(float4*)&pl[(4 * k) ^ ((ln & 7) << 2)] = ((const float4*)acc)[k];
        }
        __syncthreads();
        if (wid < half) {
            const float* pl = lds + (size_t)wid * PLANE_F + ln * 32;
#pragma unroll
            for (int k = 0; k < 8; ++k) {
                const float4 qv = *(const float4*)&pl[(4 * k) ^ ((ln & 7) << 2)];
                float4* a4 = &((float4*)acc)[k];
                a4->x *= qv.x; a4->y *= qv.y; a4->z *= qv.z; a4->w *= qv.w;
            }
        }
    }

    // ---- wave 0 stores its lane's b-row u-span (128B contiguous per lane) ----
    if (wid == 0) {
        float* po = out + (size_t)(bblk + ln) * UNITS + ublk;
#pragma unroll
        for (int k = 0; k < 8; ++k)
            *(float4*)(po + 4 * k) = ((const float4*)acc)[k];
    }
}

extern "C" void kernel_launch(void* const* d_in, const int* in_sizes, int n_in,
                              void* d_out, int out_size, void* d_ws, size_t ws_size,
                              hipStream_t stream) {
    const float* x = (const float*)d_in[0];        // 2048*256
    const float* w = (const float*)d_in[1];        // 256*512
    float* out     = (float*)d_out;                // 2048*512

    dim3 grid(UNITS / UT, B_DIM / BT);             // (16, 32) = 512 blocks
    prodw_kernel<<<grid, BLOCK, 0, stream>>>(x, w, out);
}

// Round 10
// 70.105 us; speedup vs baseline: 1.0656x; 1.0656x over previous
//
#include <hip/hip_runtime.h>

// out[b,u] = prod_i ( x[b,i]*w[i,u] + (1 - w[i,u]) ) = prod_i ( 1 + w[i,u]*(x[b,i]-1) )
// B=2048, IN_DIM=256, UNITS=512
//
// Round 16: FINAL — revert to the best-measured kernel (round-2 build,
// 70.51 us, absmax 3.76e-37). Roofline evidence (R9-R15): main loop
// REP-measured at 13.4 us; operand path {LDS,VMEM,SMEM}, occupancy {4,8
// waves/SIMD}, barriers {8,0}, packing {compiler,forced VOP3P} ALL neutral
// => VALU-slot-bound at the measured f32 FMA ceiling (2 slots/term is the
// algebraic floor; no fp32 MFMA on CDNA4; product-reduce has no matrix
// mapping). dur_us is dominated by ~57 us of harness fixed cost (41 us
// workspace re-poison fill + dispatch overhead) outside kernel control.
//
// Structure: 512 threads = 16 i-slices x 32 cell-threads; per thread
// 8b x 8u x 16i; x staged once transposed as-is; w double-buffered via
// global_load_lds w16 (pre-swizzled source, linear LDS dest), one barrier
// per chunk; binary-tree LDS combine; slice 0 stores.

typedef float v2f __attribute__((ext_vector_type(2)));

#define B_DIM   2048
#define IN_DIM  256
#define UNITS   512
#define BT      32      // block tile b
#define UT      64      // block tile u
#define BLOCK   512
#define NSL     16      // i-slices per block
#define KIS     16      // i per slice
#define CHUNK   4       // i per slice per w chunk
#define NCH     4       // chunks (KIS/CHUNK)
#define PSTR    68      // combine plane: per-thread float stride (4-way max)
#define PLANE   (32*PSTR)

#define XS_F    (IN_DIM*32)   // 8192 floats: y = x-1, [i][b]
#define WBUF_F  (64*64)       // 4096 floats per w chunk buffer (64 rows x 64 u)
#define LDS_F   (8*PLANE)     // 17408 >= XS_F + 2*WBUF_F (16384)

__global__ __launch_bounds__(BLOCK, 4) void prodw_kernel(
    const float* __restrict__ x,   // [B, IN_DIM]
    const float* __restrict__ w,   // [IN_DIM, UNITS]
    float* __restrict__ out)       // [B, UNITS]
{
    __shared__ __align__(16) float lds[LDS_F];
    float* __restrict__ xs  = lds;                    // [256][32]
    float* __restrict__ ws0 = lds + XS_F;             // [64][64] chunk buf A
    float* __restrict__ ws1 = lds + XS_F + WBUF_F;    // [64][64] chunk buf B

    const int tid = threadIdx.x;
    const int s   = tid >> 5;        // i-slice 0..15
    const int t   = tid & 31;        // cell-thread 0..31
    const int tb  = t >> 3;          // b-octet 0..3
    const int tu  = t & 7;           // u-octet 0..7
    const int wv  = tid >> 6;        // wave 0..7
    const int ln  = tid & 63;        // lane 0..63
    const int ublk = blockIdx.x * UT;
    const int bblk = blockIdx.y * BT;

    // ---- per-lane prefetch source addresses for w (2 calls/wave/chunk) ----
    const float* wsrc[2];
    int lofs[2];
#pragma unroll
    for (int k = 0; k < 2; ++k) {
        const int seg = wv * 2 + k;
        const int r   = seg * 4 + (ln >> 4);       // 0..63
        const int ss  = r >> 2;                    // slice 0..15
        const int ii  = r & 3;
        const int xr  = (ss & 1) << 2;
        const int col = ((ln & 15) * 4) ^ xr;
        wsrc[k] = w + (size_t)(ss * KIS + ii) * UNITS + ublk + col;
        lofs[k] = seg * 256;                       // wave-uniform
    }

    // ---- issue w chunk 0 into ws0 (async, drains at first barrier) ----
#pragma unroll
    for (int k = 0; k < 2; ++k)
        __builtin_amdgcn_global_load_lds(
            (const __attribute__((address_space(1))) void*)(wsrc[k]),
            (__attribute__((address_space(3))) void*)(ws0 + lofs[k]), 16, 0, 0);

    // ---- stage ALL of x once, transposed, as y = x-1 ----
#pragma unroll
    for (int r = 0; r < 4; ++r) {
        const int idx  = r * BLOCK + tid;          // 0..2047
        const int b    = idx & 31;
        const int srow = idx >> 5;                 // 0..63 (i quad)
        const float4 f = *(const float4*)
            (x + (size_t)(bblk + b) * IN_DIM + srow * 4);
        const int row = srow * 4;
        xs[(row + 0) * 32 + b] = f.x - 1.0f;
        xs[(row + 1) * 32 + b] = f.y - 1.0f;
        xs[(row + 2) * 32 + b] = f.z - 1.0f;
        xs[(row + 3) * 32 + b] = f.w - 1.0f;
    }

    __align__(16) float af[64];      // acc tile [jb][ju]
    v2f* __restrict__ acc = (v2f*)af;
#pragma unroll
    for (int k = 0; k < 32; ++k) acc[k] = (v2f){1.0f, 1.0f};

    const int swz = (s & 1) << 2;    // compute-side w col swizzle

    __syncthreads();   // x staged (lgkm) + w chunk0 landed (vmcnt drain)

#pragma unroll
    for (int c = 0; c < NCH; ++c) {
        float* const wcur = (c & 1) ? ws1 : ws0;
        float* const wnxt = (c & 1) ? ws0 : ws1;

        // issue next chunk's w loads NOW; they complete by this chunk's barrier
        if (c + 1 < NCH) {
            const size_t coff = (size_t)(c + 1) * CHUNK * UNITS;
#pragma unroll
            for (int k = 0; k < 2; ++k)
                __builtin_amdgcn_global_load_lds(
                    (const __attribute__((address_space(1))) void*)(wsrc[k] + coff),
                    (__attribute__((address_space(3))) void*)(wnxt + lofs[k]),
                    16, 0, 0);
        }

        // ---- compute this chunk's 4 i for slice s ----
#pragma unroll
        for (int ii = 0; ii < CHUNK; ++ii) {
            const int xrow = s * KIS + c * CHUNK + ii;   // global i
            const int wrow = s * CHUNK + ii;             // row in chunk buf
            const float4 ya = *(const float4*)&xs[xrow * 32 + tb * 8];
            const float4 yb = *(const float4*)&xs[xrow * 32 + tb * 8 + 4];
            const float4 w0 = *(const float4*)&wcur[wrow * 64 + ((tu * 8) ^ swz)];
            const float4 w1 = *(const float4*)&wcur[wrow * 64 + ((tu * 8 + 4) ^ swz)];

            v2f wvv[4] = {{w0.x, w0.y}, {w0.z, w0.w}, {w1.x, w1.y}, {w1.z, w1.w}};
            const float yv[8] = {ya.x, ya.y, ya.z, ya.w, yb.x, yb.y, yb.z, yb.w};

#pragma unroll
            for (int jb = 0; jb < 8; ++jb) {
                const v2f yy = {yv[jb], yv[jb]};
#pragma unroll
                for (int q = 0; q < 4; ++q)
                    acc[jb * 4 + q] *= __builtin_elementwise_fma(
                        yy, wvv[q], (v2f){1.0f, 1.0f});
            }
        }
        __syncthreads();   // readers done with wcur; wnxt loads drained
    }

    // ---- binary-tree combine of 16 slice partials through LDS ----
#pragma unroll
    for (int half = NSL / 2; half >= 1; half >>= 1) {
        __syncthreads();
        if (s >= half && s < 2 * half) {
            float* __restrict__ pl = lds + (size_t)(s - half) * PLANE + t * PSTR;
#pragma unroll
            for (int k = 0; k < 16; ++k)
                *(float4*)&pl[k * 4] = ((const float4*)af)[k];
        }
        __syncthreads();
        if (s < half) {
            const float* __restrict__ pl = lds + (size_t)s * PLANE + t * PSTR;
#pragma unroll
            for (int k = 0; k < 16; ++k) {
                const float4 q = *(const float4*)&pl[k * 4];
                float4* a4 = &((float4*)af)[k];
                a4->x *= q.x; a4->y *= q.y; a4->z *= q.z; a4->w *= q.w;
            }
        }
    }

    // ---- slice 0 stores the 32x64 block tile ----
    if (s == 0) {
#pragma unroll
        for (int jb = 0; jb < 8; ++jb) {
            float* __restrict__ po =
                out + (size_t)(bblk + tb * 8 + jb) * UNITS + ublk + tu * 8;
            *(float4*)(po)     = *(const float4*)&af[jb * 8];
            *(float4*)(po + 4) = *(const float4*)&af[jb * 8 + 4];
        }
    }
}

extern "C" void kernel_launch(void* const* d_in, const int* in_sizes, int n_in,
                              void* d_out, int out_size, void* d_ws, size_t ws_size,
                              hipStream_t stream) {
    const float* x = (const float*)d_in[0];        // 2048*256
    const float* w = (const float*)d_in[1];        // 256*512
    float* out     = (float*)d_out;                // 2048*512

    dim3 grid(UNITS / UT, B_DIM / BT);             // (8, 64) = 512 blocks
    prodw_kernel<<<grid, BLOCK, 0, stream>>>(x, w, out);
}